// Round 2
// baseline (262.845 us; speedup 1.0000x reference)
//
#include <hip/hip_runtime.h>

// ---------------------------------------------------------------------------
// CapsuleSequenceToGraph, fp32 in/out. B=64, T={128,512,256,256}, n=32, d=16.
// Identity: b_k[b,t,n] = <Vcum_k[b,n,:], pri[b,t,n,:]>, Vcum_k = sum_{i<k} v_i.
//
// Two kernels:
//   1) pri_kernel: pri = x @ W (bf16 MFMA), pri ws layout per mod:
//      [t][b][n*16+d] bf16 (row = 512 shorts = 1KB).
//   2) route_kernel: ONE block per (mod,b) pair (256 blocks, 1024 thr).
//      All 4 routing passes in-block; Vcum and partial sums live in LDS.
//      No P buffer, no Vcum global traffic, no inter-pass launches.
//      t-loop is software-pipelined (prefetch next 2 rows before compute).
// ---------------------------------------------------------------------------

typedef __attribute__((ext_vector_type(8))) short short8;
typedef __attribute__((ext_vector_type(4))) float floatx4;

#define PRI_BYTES 75497472ull

static __device__ __forceinline__ unsigned short f2bf(float f) {
  union { float f; unsigned int i; } v;
  v.f = f;
  unsigned int x = v.i;
  return (unsigned short)((x + 0x7fffu + ((x >> 16) & 1u)) >> 16);  // RNE
}

// ---------------------------------------------------------------------------
// pri = x @ W per t, bf16 MFMA 16x16x32. Block = (t, 16-n half): M=64(b) x
// N=256(nd) x K=64(j). Stores go through a per-wave LDS transpose so global
// writes are coalesced dwordx4 (1KB/inst).
// ---------------------------------------------------------------------------
__global__ __launch_bounds__(256) void pri_kernel(
    const float* __restrict__ x0, const float* __restrict__ x1,
    const float* __restrict__ x2, const float* __restrict__ x3,
    const float* __restrict__ w0, const float* __restrict__ w1,
    const float* __restrict__ w2, const float* __restrict__ w3,
    unsigned short* __restrict__ priAll) {
  __shared__ unsigned short wb[256 * 72];   // [nd_local][j] bf16, pitch 72
  __shared__ unsigned short sc[4][16][136]; // per-wave store-transpose scratch

  int blk = blockIdx.x;
  int tid = threadIdx.x;

  int tpair = blk >> 1, half = blk & 1;
  const float* x;
  const float* W;
  unsigned short* priT;
  int T, t;
  if (tpair < 128)      { x = x0; W = w0; priT = priAll;               T = 128; t = tpair; }
  else if (tpair < 640) { x = x1; W = w1; priT = priAll + 4194304ull;  T = 512; t = tpair - 128; }
  else if (tpair < 896) { x = x2; W = w2; priT = priAll + 20971520ull; T = 256; t = tpair - 640; }
  else                  { x = x3; W = w3; priT = priAll + 29360128ull; T = 256; t = tpair - 896; }
  priT += (size_t)t * 32768;

  // ---- stage W[t, half*16 .. +16, :, :] -> wb[nd_local][j] bf16 ----
  {
    const floatx4* Wf4 = (const floatx4*)(W + (size_t)t * 32768);
    unsigned int* wb32 = (unsigned int*)wb;  // pitch 36 dwords
#pragma unroll
    for (int it = 0; it < 8; ++it) {
      int idx = it * 256 + tid;              // 0..2047
      int nl = idx >> 7, jp = (idx >> 2) & 31, dq = idx & 3;
      int ng = half * 16 + nl;
      floatx4 fa = Wf4[ng * 256 + (2 * jp) * 4 + dq];
      floatx4 fb = Wf4[ng * 256 + (2 * jp + 1) * 4 + dq];
      int rbase = nl * 16 + dq * 4;
#pragma unroll
      for (int k = 0; k < 4; ++k) {
        unsigned int dw = (unsigned int)f2bf(fa[k]) | ((unsigned int)f2bf(fb[k]) << 16);
        wb32[(rbase + k) * 36 + jp] = dw;
      }
    }
  }

  // ---- A fragments: x[b = mt*16+m][k = s*32 + q*8 + i] -> bf16 ----
  int lane = tid & 63, mt = tid >> 6;
  int m = lane & 15, q = lane >> 4;
  short8 afrag[2];
  {
    const float* xrow = x + ((size_t)(mt * 16 + m) * T + t) * 64;
#pragma unroll
    for (int s = 0; s < 2; ++s) {
      const floatx4* xp = (const floatx4*)(xrow + s * 32 + q * 8);
      floatx4 u0 = xp[0], u1 = xp[1];
      afrag[s][0] = (short)f2bf(u0[0]); afrag[s][1] = (short)f2bf(u0[1]);
      afrag[s][2] = (short)f2bf(u0[2]); afrag[s][3] = (short)f2bf(u0[3]);
      afrag[s][4] = (short)f2bf(u1[0]); afrag[s][5] = (short)f2bf(u1[1]);
      afrag[s][6] = (short)f2bf(u1[2]); afrag[s][7] = (short)f2bf(u1[3]);
    }
  }
  __syncthreads();

  // ---- 16 N-tiles; D layout: row b = mt*16+q*4+reg, col nd = nt*16+m ----
  for (int g = 0; g < 2; ++g) {
#pragma unroll
    for (int k = 0; k < 8; ++k) {
      int nt = g * 8 + k;
      const short8* b0p = (const short8*)&wb[(nt * 16 + m) * 72 + q * 8];
      const short8* b1p = (const short8*)&wb[(nt * 16 + m) * 72 + 32 + q * 8];
      short8 bf0 = *b0p, bf1 = *b1p;
      floatx4 acc = {0.f, 0.f, 0.f, 0.f};
      acc = __builtin_amdgcn_mfma_f32_16x16x32_bf16(afrag[0], bf0, acc, 0, 0, 0);
      acc = __builtin_amdgcn_mfma_f32_16x16x32_bf16(afrag[1], bf1, acc, 0, 0, 0);
#pragma unroll
      for (int reg = 0; reg < 4; ++reg)
        sc[mt][q * 4 + reg][k * 16 + m] = f2bf(acc[reg]);
    }
#pragma unroll
    for (int i = 0; i < 4; ++i) {
      int bl = (lane >> 4) + i * 4;
      int sh = (lane & 15) * 8;
      short8 v = *(const short8*)&sc[mt][bl][sh];
      *(short8*)(priT + (size_t)(mt * 16 + bl) * 512 + half * 256 + g * 128 + sh) = v;
    }
  }
}

// ---------------------------------------------------------------------------
// route_kernel: block = one (mod, b) pair. 1024 threads = 32 groups of 32.
// Group g owns t rows {g*2, g*2+1, g*2+64, ...}. All 4 routing passes run
// inside the block; Vcum kept in LDS (pitch-17 swizzle, conflict-free).
// Per pass: logit = <Vc, p>, softmax over 32 lanes (n), acc += rc*p;
// cross-group reduce in LDS; v = tanh(S); Vcum += v (or write out, pass 3).
// LDS ~84KB -> exactly 1 block/CU (256 blocks on 256 CUs).
// ---------------------------------------------------------------------------
__global__ __launch_bounds__(1024) void route_kernel(
    const unsigned short* __restrict__ priAll, float* __restrict__ out) {
  __shared__ float Sl[32][640];   // [group][n*17+d], pitch 640 (occupancy pin)
  __shared__ float Vc_s[544];     // Vcum, [n*17+d]

  int blk = blockIdx.x;
  int mod = blk & 3, b = blk >> 2;
  size_t poff; int T;
  if (mod == 0)      { poff = 0ull;         T = 128; }
  else if (mod == 1) { poff = 4194304ull;   T = 512; }
  else if (mod == 2) { poff = 20971520ull;  T = 256; }
  else               { poff = 29360128ull;  T = 256; }

  const unsigned short* priM = priAll + poff + (size_t)b * 512;

  int tid = threadIdx.x;
  int n = tid & 31, g = tid >> 5;
  int nbase = n * 17;

  if (tid < 544) Vc_s[tid] = 0.f;
  __syncthreads();

  for (int pass = 0; pass < 4; ++pass) {
    float Vc[16];
#pragma unroll
    for (int d = 0; d < 16; ++d) Vc[d] = Vc_s[nbase + d];

    float acc[16];
#pragma unroll
    for (int d = 0; d < 16; ++d) acc[d] = 0.f;

    // software-pipelined t loop: prefetch next 2 rows before computing current
    const unsigned short* pr = priM + (size_t)(g * 2) * 32768 + n * 16;
    uint4 c0a = ((const uint4*)pr)[0], c0b = ((const uint4*)pr)[1];
    uint4 c1a = ((const uint4*)(pr + 32768))[0], c1b = ((const uint4*)(pr + 32768))[1];

    for (int t0 = g * 2; t0 < T; t0 += 64) {
      uint4 n0a, n0b, n1a, n1b;
      if (t0 + 64 < T) {  // wave-uniform (T % 64 == 0, g*2 < 64)
        const unsigned short* pn = priM + (size_t)(t0 + 64) * 32768 + n * 16;
        n0a = ((const uint4*)pn)[0]; n0b = ((const uint4*)pn)[1];
        n1a = ((const uint4*)(pn + 32768))[0]; n1b = ((const uint4*)(pn + 32768))[1];
      }

#pragma unroll
      for (int tt = 0; tt < 2; ++tt) {
        uint4 ca = tt ? c1a : c0a;
        uint4 cb = tt ? c1b : c0b;
        float p[16];
        {
          unsigned int wds[8] = {ca.x, ca.y, ca.z, ca.w, cb.x, cb.y, cb.z, cb.w};
#pragma unroll
          for (int k = 0; k < 8; ++k) {
            union { unsigned int u; float f; } lo, hi;
            lo.u = wds[k] << 16;
            hi.u = wds[k] & 0xffff0000u;
            p[2 * k] = lo.f;
            p[2 * k + 1] = hi.f;
          }
        }
        float logit = 0.f;
#pragma unroll
        for (int d = 0; d < 16; ++d) logit += p[d] * Vc[d];
        float mx = logit;
#pragma unroll
        for (int o = 16; o >= 1; o >>= 1) mx = fmaxf(mx, __shfl_xor(mx, o, 32));
        float e = __expf(logit - mx);
        float s = e;
#pragma unroll
        for (int o = 16; o >= 1; o >>= 1) s += __shfl_xor(s, o, 32);
        float rc = e / s;
#pragma unroll
        for (int d = 0; d < 16; ++d) acc[d] += rc * p[d];
      }

      if (t0 + 64 < T) { c0a = n0a; c0b = n0b; c1a = n1a; c1b = n1b; }
    }

#pragma unroll
    for (int d = 0; d < 16; ++d) Sl[g][nbase + d] = acc[d];
    __syncthreads();

    if (tid < 512) {
      int nn = tid >> 4, dd = tid & 15;
      int idx = nn * 17 + dd;
      float s = 0.f;
#pragma unroll
      for (int gg = 0; gg < 32; ++gg) s += Sl[gg][idx];
      float v = tanhf(s);
      if (pass == 3) out[(size_t)(mod * 64 + b) * 512 + tid] = v;
      else Vc_s[idx] += v;
    }
    __syncthreads();
  }
}

extern "C" void kernel_launch(void* const* d_in, const int* in_sizes, int n_in,
                              void* d_out, int out_size, void* d_ws, size_t ws_size,
                              hipStream_t stream) {
  const float* x0 = (const float*)d_in[0];
  const float* x1 = (const float*)d_in[1];
  const float* x2 = (const float*)d_in[2];
  const float* x3 = (const float*)d_in[3];
  const float* w0 = (const float*)d_in[4];
  const float* w1 = (const float*)d_in[5];
  const float* w2 = (const float*)d_in[6];
  const float* w3 = (const float*)d_in[7];

  unsigned short* pri = (unsigned short*)d_ws;

  pri_kernel<<<2304, 256, 0, stream>>>(x0, x1, x2, x3, w0, w1, w2, w3, pri);
  route_kernel<<<256, 1024, 0, stream>>>(pri, (float*)d_out);
}

// Round 3
// 249.299 us; speedup vs baseline: 1.0543x; 1.0543x over previous
//
#include <hip/hip_runtime.h>

// ---------------------------------------------------------------------------
// CapsuleSequenceToGraph, fp32 in/out. B=64, T={128,512,256,256}, n=32, d=16.
// Identity: b_k[b,t,n] = <Vcum_k[b,n,:], pri[b,t,n,:]>, Vcum_k = sum_{i<k} v_i.
//
// Two kernels:
//   1) pri_kernel: pri = x @ W (bf16 MFMA). Block = (t-PAIR, 16-n half),
//      software-pipelined: W(t1) global loads are in flight during t0's
//      MFMA/store phase, so HBM streams during compute (was phase-serialized
//      at 2.1 TB/s / 80us). All staging loads are explicit register arrays
//      (16 x floatx4 in flight; old VGPR=68 build serialized them).
//   2) route_kernel: ONE block per (mod,b) pair (256 blocks, 1024 thr).
//      All 4 routing passes in-block; Vcum + partials in LDS. Register
//      window trimmed to 1 t-row/group/iter (+1-row prefetch) to stay well
//      under the 128-VGPR cap of a 1024-thread block (spill suspect at ~78us).
// ---------------------------------------------------------------------------

typedef __attribute__((ext_vector_type(8))) short short8;
typedef __attribute__((ext_vector_type(4))) float floatx4;

static __device__ __forceinline__ unsigned short f2bf(float f) {
  union { float f; unsigned int i; } v;
  v.f = f;
  unsigned int x = v.i;
  return (unsigned short)((x + 0x7fffu + ((x >> 16) & 1u)) >> 16);  // RNE
}

// ---------------------------------------------------------------------------
// pri = x @ W, bf16 MFMA 16x16x32. Block = (t-pair, half): per t, M=64(b) x
// N=256(nd) x K=64(j). 1152 blocks. LDS 53KB -> 3 blocks/CU.
// ---------------------------------------------------------------------------
__global__ __launch_bounds__(256) void pri_kernel(
    const float* __restrict__ x0, const float* __restrict__ x1,
    const float* __restrict__ x2, const float* __restrict__ x3,
    const float* __restrict__ w0, const float* __restrict__ w1,
    const float* __restrict__ w2, const float* __restrict__ w3,
    unsigned short* __restrict__ priAll) {
  __shared__ unsigned short wb[256 * 72];   // [nd_local][j] bf16, pitch 72
  __shared__ unsigned short sc[4][16][136]; // per-wave store-transpose scratch

  int blk = blockIdx.x;
  int tid = threadIdx.x;

  int pair = blk >> 1, half = blk & 1;
  const float* x;
  const float* W;
  unsigned short* priT;
  int T, t0;
  if (pair < 64)       { x = x0; W = w0; priT = priAll;               T = 128; t0 = 2 * pair; }
  else if (pair < 320) { x = x1; W = w1; priT = priAll + 4194304ull;  T = 512; t0 = 2 * (pair - 64); }
  else if (pair < 448) { x = x2; W = w2; priT = priAll + 20971520ull; T = 256; t0 = 2 * (pair - 320); }
  else                 { x = x3; W = w3; priT = priAll + 29360128ull; T = 256; t0 = 2 * (pair - 448); }
  unsigned short* priT0 = priT + (size_t)t0 * 32768;
  unsigned short* priT1 = priT + (size_t)(t0 + 1) * 32768;

  int lane = tid & 63, mt = tid >> 6;
  int m = lane & 15, q = lane >> 4;

  // ---- issue x loads for BOTH t (8 x floatx4, in flight together) ----
  floatx4 xv[8];
  {
    const float* xrow = x + ((size_t)(mt * 16 + m) * T + t0) * 64;
#pragma unroll
    for (int tt = 0; tt < 2; ++tt)
#pragma unroll
      for (int s = 0; s < 2; ++s) {
        const floatx4* xp = (const floatx4*)(xrow + tt * 64 + s * 32 + q * 8);
        xv[tt * 4 + s * 2]     = xp[0];
        xv[tt * 4 + s * 2 + 1] = xp[1];
      }
  }

  // ---- issue W(t0) loads: 16 floatx4 explicitly in flight ----
  floatx4 wra[8], wrb[8];
  {
    const floatx4* Wf = (const floatx4*)(W + (size_t)t0 * 32768);
#pragma unroll
    for (int it = 0; it < 8; ++it) {
      int idx = it * 256 + tid;              // 0..2047
      int nl = idx >> 7, jp = (idx >> 2) & 31, dq = idx & 3;
      int ng = half * 16 + nl;
      wra[it] = Wf[ng * 256 + (2 * jp) * 4 + dq];
      wrb[it] = Wf[ng * 256 + (2 * jp + 1) * 4 + dq];
    }
  }

  // ---- build A fragments for both t while W loads fly ----
  short8 afrag[2][2];  // [tt][s]
#pragma unroll
  for (int tt = 0; tt < 2; ++tt)
#pragma unroll
    for (int s = 0; s < 2; ++s) {
      floatx4 u0 = xv[tt * 4 + s * 2], u1 = xv[tt * 4 + s * 2 + 1];
      short8 a;
      a[0] = (short)f2bf(u0[0]); a[1] = (short)f2bf(u0[1]);
      a[2] = (short)f2bf(u0[2]); a[3] = (short)f2bf(u0[3]);
      a[4] = (short)f2bf(u1[0]); a[5] = (short)f2bf(u1[1]);
      a[6] = (short)f2bf(u1[2]); a[7] = (short)f2bf(u1[3]);
      afrag[tt][s] = a;
    }

  unsigned int* wb32 = (unsigned int*)wb;  // pitch 36 dwords

  // ---- convert + write wb(t0) ----
#pragma unroll
  for (int it = 0; it < 8; ++it) {
    int idx = it * 256 + tid;
    int nl = idx >> 7, jp = (idx >> 2) & 31, dq = idx & 3;
    int rbase = nl * 16 + dq * 4;
#pragma unroll
    for (int k = 0; k < 4; ++k) {
      unsigned int dw = (unsigned int)f2bf(wra[it][k]) | ((unsigned int)f2bf(wrb[it][k]) << 16);
      wb32[(rbase + k) * 36 + jp] = dw;
    }
  }
  __syncthreads();

  // ---- issue W(t1) loads NOW (in flight across t0 compute) ----
  {
    const floatx4* Wf = (const floatx4*)(W + (size_t)(t0 + 1) * 32768);
#pragma unroll
    for (int it = 0; it < 8; ++it) {
      int idx = it * 256 + tid;
      int nl = idx >> 7, jp = (idx >> 2) & 31, dq = idx & 3;
      int ng = half * 16 + nl;
      wra[it] = Wf[ng * 256 + (2 * jp) * 4 + dq];
      wrb[it] = Wf[ng * 256 + (2 * jp + 1) * 4 + dq];
    }
  }

  // ---- compute one t: 16 N-tiles; D: row b = mt*16+q*4+reg, col nd = nt*16+m
  auto compute_t = [&](const short8& a0, const short8& a1, unsigned short* dst) {
    for (int g2 = 0; g2 < 2; ++g2) {
#pragma unroll
      for (int k = 0; k < 8; ++k) {
        int nt = g2 * 8 + k;
        const short8* b0p = (const short8*)&wb[(nt * 16 + m) * 72 + q * 8];
        const short8* b1p = (const short8*)&wb[(nt * 16 + m) * 72 + 32 + q * 8];
        short8 bf0 = *b0p, bf1 = *b1p;
        floatx4 acc = {0.f, 0.f, 0.f, 0.f};
        acc = __builtin_amdgcn_mfma_f32_16x16x32_bf16(a0, bf0, acc, 0, 0, 0);
        acc = __builtin_amdgcn_mfma_f32_16x16x32_bf16(a1, bf1, acc, 0, 0, 0);
#pragma unroll
        for (int reg = 0; reg < 4; ++reg)
          sc[mt][q * 4 + reg][k * 16 + m] = f2bf(acc[reg]);
      }
#pragma unroll
      for (int i = 0; i < 4; ++i) {
        int bl = (lane >> 4) + i * 4;
        int sh = (lane & 15) * 8;
        short8 v = *(const short8*)&sc[mt][bl][sh];
        *(short8*)(dst + (size_t)(mt * 16 + bl) * 512 + half * 256 + g2 * 128 + sh) = v;
      }
    }
  };

  compute_t(afrag[0][0], afrag[0][1], priT0);
  __syncthreads();  // all waves done reading wb(t0)

  // ---- convert + write wb(t1) ----
#pragma unroll
  for (int it = 0; it < 8; ++it) {
    int idx = it * 256 + tid;
    int nl = idx >> 7, jp = (idx >> 2) & 31, dq = idx & 3;
    int rbase = nl * 16 + dq * 4;
#pragma unroll
    for (int k = 0; k < 4; ++k) {
      unsigned int dw = (unsigned int)f2bf(wra[it][k]) | ((unsigned int)f2bf(wrb[it][k]) << 16);
      wb32[(rbase + k) * 36 + jp] = dw;
    }
  }
  __syncthreads();

  compute_t(afrag[1][0], afrag[1][1], priT1);
}

// ---------------------------------------------------------------------------
// route_kernel: block = one (mod, b) pair. 1024 threads = 32 groups of 32.
// Group g owns t rows {g, g+32, g+64, ...} (1 row/iter + 1-row prefetch:
// ~85 live VGPRs, under the 128 cap). All 4 routing passes in-block; Vcum in
// LDS (pitch-17 swizzle). Softmax without max-subtraction (|logit| << 80).
// LDS ~84KB -> exactly 1 block/CU (256 blocks on 256 CUs).
// ---------------------------------------------------------------------------
__global__ __launch_bounds__(1024) void route_kernel(
    const unsigned short* __restrict__ priAll, float* __restrict__ out) {
  __shared__ float Sl[32][640];   // [group][n*17+d], pitch 640 (occupancy pin)
  __shared__ float Vc_s[544];     // Vcum, [n*17+d]

  int blk = blockIdx.x;
  int mod = blk & 3, b = blk >> 2;
  size_t poff; int T;
  if (mod == 0)      { poff = 0ull;         T = 128; }
  else if (mod == 1) { poff = 4194304ull;   T = 512; }
  else if (mod == 2) { poff = 20971520ull;  T = 256; }
  else               { poff = 29360128ull;  T = 256; }

  const unsigned short* priM = priAll + poff + (size_t)b * 512;

  int tid = threadIdx.x;
  int n = tid & 31, g = tid >> 5;
  int nbase = n * 17;

  if (tid < 544) Vc_s[tid] = 0.f;
  __syncthreads();

  int iters = T >> 5;  // rows per group per pass

  for (int pass = 0; pass < 4; ++pass) {
    float Vc[16];
#pragma unroll
    for (int d = 0; d < 16; ++d) Vc[d] = Vc_s[nbase + d];

    float acc[16];
#pragma unroll
    for (int d = 0; d < 16; ++d) acc[d] = 0.f;

    // row t = g + it*32; row stride = 32768 shorts = 4096 uint4
    const uint4* pr = (const uint4*)(priM + (size_t)g * 32768 + n * 16);
    uint4 ca = pr[0], cb = pr[1];

    for (int it = 0; it < iters; ++it) {
      uint4 na, nb;
      bool more = (it + 1 < iters);  // uniform across block
      if (more) { na = pr[131072]; nb = pr[131073]; }

      float p[16];
      {
        unsigned int wds[8] = {ca.x, ca.y, ca.z, ca.w, cb.x, cb.y, cb.z, cb.w};
#pragma unroll
        for (int k = 0; k < 8; ++k) {
          union { unsigned int u; float f; } lo, hi;
          lo.u = wds[k] << 16;
          hi.u = wds[k] & 0xffff0000u;
          p[2 * k] = lo.f;
          p[2 * k + 1] = hi.f;
        }
      }
      float logit = 0.f;
#pragma unroll
      for (int d = 0; d < 16; ++d) logit += p[d] * Vc[d];
      float e = __expf(logit);
      float s = e;
#pragma unroll
      for (int o = 16; o >= 1; o >>= 1) s += __shfl_xor(s, o, 32);
      float rc = e / s;
#pragma unroll
      for (int d = 0; d < 16; ++d) acc[d] += rc * p[d];

      if (more) { ca = na; cb = nb; pr += 131072; }
    }

#pragma unroll
    for (int d = 0; d < 16; ++d) Sl[g][nbase + d] = acc[d];
    __syncthreads();

    if (tid < 512) {
      int nn = tid >> 4, dd = tid & 15;
      int idx = nn * 17 + dd;
      float s = 0.f;
#pragma unroll
      for (int gg = 0; gg < 32; ++gg) s += Sl[gg][idx];
      float v = tanhf(s);
      if (pass == 3) out[(size_t)(mod * 64 + b) * 512 + tid] = v;
      else Vc_s[idx] += v;
    }
    __syncthreads();
  }
}

extern "C" void kernel_launch(void* const* d_in, const int* in_sizes, int n_in,
                              void* d_out, int out_size, void* d_ws, size_t ws_size,
                              hipStream_t stream) {
  const float* x0 = (const float*)d_in[0];
  const float* x1 = (const float*)d_in[1];
  const float* x2 = (const float*)d_in[2];
  const float* x3 = (const float*)d_in[3];
  const float* w0 = (const float*)d_in[4];
  const float* w1 = (const float*)d_in[5];
  const float* w2 = (const float*)d_in[6];
  const float* w3 = (const float*)d_in[7];

  unsigned short* pri = (unsigned short*)d_ws;

  pri_kernel<<<1152, 256, 0, stream>>>(x0, x1, x2, x3, w0, w1, w2, w3, pri);
  route_kernel<<<256, 1024, 0, stream>>>(pri, (float*)d_out);
}

// Round 4
// 241.770 us; speedup vs baseline: 1.0872x; 1.0311x over previous
//
#include <hip/hip_runtime.h>

// ---------------------------------------------------------------------------
// CapsuleSequenceToGraph, fp32 in/out. B=64, T={128,512,256,256}, n=32, d=16.
// Identity: b_k[b,t,n] = <Vcum_k[b,n,:], pri[b,t,n,:]>, Vcum_k = sum_{i<k} v_i.
//
// Two kernels:
//   1) pri_kernel: pri = x @ W (bf16 MFMA). Block = (t-PAIR, 16-n half),
//      software-pipelined: W(t1) global loads held in 64 VGPRs across t0's
//      MFMA/store phase. __launch_bounds__(256,3): LDS caps us at 3 blocks/CU
//      (12 waves = 3/SIMD), so cap VGPRs at ~168 — round-3's default build
//      allocated only 76 VGPRs and the compiler sank the prefetch to its use,
//      defeating the pipeline (measured 90us, VALUBusy 8%, HBM 1.9 TB/s).
//      W/x are single-use streams -> nontemporal loads (keep L3 for pri,
//      which route re-reads 4x).
//   2) route_kernel: ONE block per (mod,b) pair (256 blocks, 1024 thr).
//      All 4 routing passes in-block; Vcum + partials in LDS. 1 t-row/group
//      per iter + 1-row prefetch (fits 128-VGPR cap). UNCHANGED this round.
// ---------------------------------------------------------------------------

typedef __attribute__((ext_vector_type(8))) short short8;
typedef __attribute__((ext_vector_type(4))) float floatx4;

static __device__ __forceinline__ unsigned short f2bf(float f) {
  union { float f; unsigned int i; } v;
  v.f = f;
  unsigned int x = v.i;
  return (unsigned short)((x + 0x7fffu + ((x >> 16) & 1u)) >> 16);  // RNE
}

// ---------------------------------------------------------------------------
// pri = x @ W, bf16 MFMA 16x16x32. Block = (t-pair, half): per t, M=64(b) x
// N=256(nd) x K=64(j). 1152 blocks. LDS 53KB -> 3 blocks/CU.
// ---------------------------------------------------------------------------
__global__ __launch_bounds__(256, 3) void pri_kernel(
    const float* __restrict__ x0, const float* __restrict__ x1,
    const float* __restrict__ x2, const float* __restrict__ x3,
    const float* __restrict__ w0, const float* __restrict__ w1,
    const float* __restrict__ w2, const float* __restrict__ w3,
    unsigned short* __restrict__ priAll) {
  __shared__ unsigned short wb[256 * 72];   // [nd_local][j] bf16, pitch 72
  __shared__ unsigned short sc[4][16][136]; // per-wave store-transpose scratch

  int blk = blockIdx.x;
  int tid = threadIdx.x;

  int pair = blk >> 1, half = blk & 1;
  const float* x;
  const float* W;
  unsigned short* priT;
  int T, t0;
  if (pair < 64)       { x = x0; W = w0; priT = priAll;               T = 128; t0 = 2 * pair; }
  else if (pair < 320) { x = x1; W = w1; priT = priAll + 4194304ull;  T = 512; t0 = 2 * (pair - 64); }
  else if (pair < 448) { x = x2; W = w2; priT = priAll + 20971520ull; T = 256; t0 = 2 * (pair - 320); }
  else                 { x = x3; W = w3; priT = priAll + 29360128ull; T = 256; t0 = 2 * (pair - 448); }
  unsigned short* priT0 = priT + (size_t)t0 * 32768;
  unsigned short* priT1 = priT + (size_t)(t0 + 1) * 32768;

  int lane = tid & 63, mt = tid >> 6;
  int m = lane & 15, q = lane >> 4;

  // ---- issue x loads for BOTH t (8 x floatx4, in flight together) ----
  floatx4 xv[8];
  {
    const float* xrow = x + ((size_t)(mt * 16 + m) * T + t0) * 64;
#pragma unroll
    for (int tt = 0; tt < 2; ++tt)
#pragma unroll
      for (int s = 0; s < 2; ++s) {
        const floatx4* xp = (const floatx4*)(xrow + tt * 64 + s * 32 + q * 8);
        xv[tt * 4 + s * 2]     = __builtin_nontemporal_load(xp);
        xv[tt * 4 + s * 2 + 1] = __builtin_nontemporal_load(xp + 1);
      }
  }

  // ---- issue W(t0) loads: 16 floatx4 explicitly in flight ----
  floatx4 wra[8], wrb[8];
  {
    const floatx4* Wf = (const floatx4*)(W + (size_t)t0 * 32768);
#pragma unroll
    for (int it = 0; it < 8; ++it) {
      int idx = it * 256 + tid;              // 0..2047
      int nl = idx >> 7, jp = (idx >> 2) & 31, dq = idx & 3;
      int ng = half * 16 + nl;
      wra[it] = __builtin_nontemporal_load(Wf + ng * 256 + (2 * jp) * 4 + dq);
      wrb[it] = __builtin_nontemporal_load(Wf + ng * 256 + (2 * jp + 1) * 4 + dq);
    }
  }

  // ---- build A fragments for both t while W loads fly ----
  short8 afrag[2][2];  // [tt][s]
#pragma unroll
  for (int tt = 0; tt < 2; ++tt)
#pragma unroll
    for (int s = 0; s < 2; ++s) {
      floatx4 u0 = xv[tt * 4 + s * 2], u1 = xv[tt * 4 + s * 2 + 1];
      short8 a;
      a[0] = (short)f2bf(u0[0]); a[1] = (short)f2bf(u0[1]);
      a[2] = (short)f2bf(u0[2]); a[3] = (short)f2bf(u0[3]);
      a[4] = (short)f2bf(u1[0]); a[5] = (short)f2bf(u1[1]);
      a[6] = (short)f2bf(u1[2]); a[7] = (short)f2bf(u1[3]);
      afrag[tt][s] = a;
    }

  unsigned int* wb32 = (unsigned int*)wb;  // pitch 36 dwords

  // ---- convert + write wb(t0) ----
#pragma unroll
  for (int it = 0; it < 8; ++it) {
    int idx = it * 256 + tid;
    int nl = idx >> 7, jp = (idx >> 2) & 31, dq = idx & 3;
    int rbase = nl * 16 + dq * 4;
#pragma unroll
    for (int k = 0; k < 4; ++k) {
      unsigned int dw = (unsigned int)f2bf(wra[it][k]) | ((unsigned int)f2bf(wrb[it][k]) << 16);
      wb32[(rbase + k) * 36 + jp] = dw;
    }
  }
  __syncthreads();

  // ---- issue W(t1) loads NOW; they stay in VGPRs across t0 compute ----
  {
    const floatx4* Wf = (const floatx4*)(W + (size_t)(t0 + 1) * 32768);
#pragma unroll
    for (int it = 0; it < 8; ++it) {
      int idx = it * 256 + tid;
      int nl = idx >> 7, jp = (idx >> 2) & 31, dq = idx & 3;
      int ng = half * 16 + nl;
      wra[it] = __builtin_nontemporal_load(Wf + ng * 256 + (2 * jp) * 4 + dq);
      wrb[it] = __builtin_nontemporal_load(Wf + ng * 256 + (2 * jp + 1) * 4 + dq);
    }
  }

  // ---- compute one t: 16 N-tiles; D: row b = mt*16+q*4+reg, col nd = nt*16+m
  auto compute_t = [&](const short8& a0, const short8& a1, unsigned short* dst) {
    for (int g2 = 0; g2 < 2; ++g2) {
#pragma unroll
      for (int k = 0; k < 8; ++k) {
        int nt = g2 * 8 + k;
        const short8* b0p = (const short8*)&wb[(nt * 16 + m) * 72 + q * 8];
        const short8* b1p = (const short8*)&wb[(nt * 16 + m) * 72 + 32 + q * 8];
        short8 bf0 = *b0p, bf1 = *b1p;
        floatx4 acc = {0.f, 0.f, 0.f, 0.f};
        acc = __builtin_amdgcn_mfma_f32_16x16x32_bf16(a0, bf0, acc, 0, 0, 0);
        acc = __builtin_amdgcn_mfma_f32_16x16x32_bf16(a1, bf1, acc, 0, 0, 0);
#pragma unroll
        for (int reg = 0; reg < 4; ++reg)
          sc[mt][q * 4 + reg][k * 16 + m] = f2bf(acc[reg]);
      }
#pragma unroll
      for (int i = 0; i < 4; ++i) {
        int bl = (lane >> 4) + i * 4;
        int sh = (lane & 15) * 8;
        short8 v = *(const short8*)&sc[mt][bl][sh];
        *(short8*)(dst + (size_t)(mt * 16 + bl) * 512 + half * 256 + g2 * 128 + sh) = v;
      }
    }
  };

  compute_t(afrag[0][0], afrag[0][1], priT0);
  __syncthreads();  // all waves done reading wb(t0)

  // ---- convert + write wb(t1) ----
#pragma unroll
  for (int it = 0; it < 8; ++it) {
    int idx = it * 256 + tid;
    int nl = idx >> 7, jp = (idx >> 2) & 31, dq = idx & 3;
    int rbase = nl * 16 + dq * 4;
#pragma unroll
    for (int k = 0; k < 4; ++k) {
      unsigned int dw = (unsigned int)f2bf(wra[it][k]) | ((unsigned int)f2bf(wrb[it][k]) << 16);
      wb32[(rbase + k) * 36 + jp] = dw;
    }
  }
  __syncthreads();

  compute_t(afrag[1][0], afrag[1][1], priT1);
}

// ---------------------------------------------------------------------------
// route_kernel: block = one (mod, b) pair. 1024 threads = 32 groups of 32.
// Group g owns t rows {g, g+32, g+64, ...} (1 row/iter + 1-row prefetch).
// All 4 routing passes in-block; Vcum in LDS (pitch-17 swizzle). Softmax
// without max-subtraction (|logit| bounded << fp32 exp range).
// LDS ~84KB -> exactly 1 block/CU (256 blocks on 256 CUs).
// ---------------------------------------------------------------------------
__global__ __launch_bounds__(1024) void route_kernel(
    const unsigned short* __restrict__ priAll, float* __restrict__ out) {
  __shared__ float Sl[32][640];   // [group][n*17+d], pitch 640 (occupancy pin)
  __shared__ float Vc_s[544];     // Vcum, [n*17+d]

  int blk = blockIdx.x;
  int mod = blk & 3, b = blk >> 2;
  size_t poff; int T;
  if (mod == 0)      { poff = 0ull;         T = 128; }
  else if (mod == 1) { poff = 4194304ull;   T = 512; }
  else if (mod == 2) { poff = 20971520ull;  T = 256; }
  else               { poff = 29360128ull;  T = 256; }

  const unsigned short* priM = priAll + poff + (size_t)b * 512;

  int tid = threadIdx.x;
  int n = tid & 31, g = tid >> 5;
  int nbase = n * 17;

  if (tid < 544) Vc_s[tid] = 0.f;
  __syncthreads();

  int iters = T >> 5;  // rows per group per pass

  for (int pass = 0; pass < 4; ++pass) {
    float Vc[16];
#pragma unroll
    for (int d = 0; d < 16; ++d) Vc[d] = Vc_s[nbase + d];

    float acc[16];
#pragma unroll
    for (int d = 0; d < 16; ++d) acc[d] = 0.f;

    // row t = g + it*32; row stride = 32768 shorts = 4096 uint4
    const uint4* pr = (const uint4*)(priM + (size_t)g * 32768 + n * 16);
    uint4 ca = pr[0], cb = pr[1];

    for (int it = 0; it < iters; ++it) {
      uint4 na, nb;
      bool more = (it + 1 < iters);  // uniform across block
      if (more) { na = pr[131072]; nb = pr[131073]; }

      float p[16];
      {
        unsigned int wds[8] = {ca.x, ca.y, ca.z, ca.w, cb.x, cb.y, cb.z, cb.w};
#pragma unroll
        for (int k = 0; k < 8; ++k) {
          union { unsigned int u; float f; } lo, hi;
          lo.u = wds[k] << 16;
          hi.u = wds[k] & 0xffff0000u;
          p[2 * k] = lo.f;
          p[2 * k + 1] = hi.f;
        }
      }
      float logit = 0.f;
#pragma unroll
      for (int d = 0; d < 16; ++d) logit += p[d] * Vc[d];
      float e = __expf(logit);
      float s = e;
#pragma unroll
      for (int o = 16; o >= 1; o >>= 1) s += __shfl_xor(s, o, 32);
      float rc = e / s;
#pragma unroll
      for (int d = 0; d < 16; ++d) acc[d] += rc * p[d];

      if (more) { ca = na; cb = nb; pr += 131072; }
    }

#pragma unroll
    for (int d = 0; d < 16; ++d) Sl[g][nbase + d] = acc[d];
    __syncthreads();

    if (tid < 512) {
      int nn = tid >> 4, dd = tid & 15;
      int idx = nn * 17 + dd;
      float s = 0.f;
#pragma unroll
      for (int gg = 0; gg < 32; ++gg) s += Sl[gg][idx];
      float v = tanhf(s);
      if (pass == 3) out[(size_t)(mod * 64 + b) * 512 + tid] = v;
      else Vc_s[idx] += v;
    }
    __syncthreads();
  }
}

extern "C" void kernel_launch(void* const* d_in, const int* in_sizes, int n_in,
                              void* d_out, int out_size, void* d_ws, size_t ws_size,
                              hipStream_t stream) {
  const float* x0 = (const float*)d_in[0];
  const float* x1 = (const float*)d_in[1];
  const float* x2 = (const float*)d_in[2];
  const float* x3 = (const float*)d_in[3];
  const float* w0 = (const float*)d_in[4];
  const float* w1 = (const float*)d_in[5];
  const float* w2 = (const float*)d_in[6];
  const float* w3 = (const float*)d_in[7];

  unsigned short* pri = (unsigned short*)d_ws;

  pri_kernel<<<1152, 256, 0, stream>>>(x0, x1, x2, x3, w0, w1, w2, w3, pri);
  route_kernel<<<256, 1024, 0, stream>>>(pri, (float*)d_out);
}